// Round 4
// baseline (615.202 us; speedup 1.0000x reference)
//
#include <hip/hip_runtime.h>
#include <stdint.h>
#include <math.h>

// B=8, N=2048, H=1024, 2H=2048, M=B*N=16384
#define NB 8
#define NN 2048
#define HH 1024
#define K2 2048
#define MM 16384

typedef unsigned short u16;
typedef __attribute__((ext_vector_type(8))) short short8v;
typedef __attribute__((ext_vector_type(4))) float floatx4;

__device__ __forceinline__ float bf2f(u16 u) { return __uint_as_float(((unsigned)u) << 16); }
__device__ __forceinline__ u16 f2bf(float f) {
  unsigned u = __float_as_uint(f);
  unsigned r = (u + 0x7fffu + ((u >> 16) & 1u)) >> 16;
  return (u16)r;
}

__device__ __forceinline__ void async16(const void* g, void* lds) {
  __builtin_amdgcn_global_load_lds((const __attribute__((address_space(1))) void*)g,
                                   (__attribute__((address_space(3))) void*)lds,
                                   16, 0, 0);
}

// bijective XCD swizzle: grids here are all multiples of 8
__device__ __forceinline__ int xcd_swz(int bid, int nblk) {
  return (bid & 7) * (nblk >> 3) + (bid >> 3);
}

#define SBAR() __builtin_amdgcn_sched_barrier(0)

// ======================================================================
// 256x256 tile GEMM core, phase schedule (T3+T4) pinned with
// sched_barrier(0) per guide rule #18 (compiler hoists register-only
// MFMA past inline-asm lgkmcnt despite "memory" clobber; phases are
// fiction without the fences). Ring-3 LDS, 8 waves (2M x 4N), BK=32.
// Per K-tile: 2 phases, each
//   {ds_read b128 x4-8 ; issue 2 global_load_lds ; SBAR ; barrier ;
//    lgkmcnt(0) ; SBAR ; setprio(1) ; 16 MFMA ; setprio(0) ; SBAR ; barrier}
// Counted vmcnt(4) once per K-tile. Staging distance 2 K-tiles (ring-3).
// LDS tile: 256 rows x 32 cols bf16, 64B rows, 16B-chunk XOR swizzle
// phys = chunk ^ ((row>>1)&3); 0 bank conflicts (verified round 2).
// ======================================================================
__device__ __forceinline__ void gemm256_core(const u16* __restrict__ A, int lda,
                                             const u16* __restrict__ Bt, int ldb,
                                             int rowA0, int rowB0, int K,
                                             u16* sA, u16* sB, floatx4 acc[8][4]) {
  const int t = threadIdx.x;       // 0..511
  const int w = t >> 6, l = t & 63;
  const int wr = w >> 2, wc = w & 3;

#pragma unroll
  for (int mi = 0; mi < 8; mi++)
#pragma unroll
    for (int ni = 0; ni < 4; ni++) { floatx4 z = {0.f,0.f,0.f,0.f}; acc[mi][ni] = z; }

  // staging: thread t covers LDS rows (t>>2) and 128+(t>>2); source chunk pre-swizzled
  const int cS = ((t & 3) ^ ((t >> 3) & 3)) << 3;
  const u16* gA0 = A + (size_t)(rowA0 + (t >> 2)) * lda + cS;
  const u16* gA1 = A + (size_t)(rowA0 + 128 + (t >> 2)) * lda + cS;
  const u16* gB0 = Bt + (size_t)(rowB0 + (t >> 2)) * ldb + cS;
  const u16* gB1 = Bt + (size_t)(rowB0 + 128 + (t >> 2)) * ldb + cS;
  char* dA = (char*)sA + (w << 10) + (l << 4);
  char* dB = (char*)sB + (w << 10) + (l << 4);

  // read-side addressing (swizzled)
  const int fr = l & 15;
  const int ch = (((l >> 4) ^ ((fr >> 1) & 3)) << 4);
  const int abase = (wr * 128 + fr) * 64 + ch;     // + mi*1024
  const int bbase = (wc * 64 + fr) * 64 + ch;      // + ni*1024

  const int NT = K >> 5;

#define STGA(bi, kt) { const int ko_ = (kt) << 5; char* d_ = dA + (bi) * 16384; \
    async16(gA0 + ko_, d_); async16(gA1 + ko_, d_ + 8192); }
#define STGB(bi, kt) { const int ko_ = (kt) << 5; char* d_ = dB + (bi) * 16384; \
    async16(gB0 + ko_, d_); async16(gB1 + ko_, d_ + 8192); }

  // prologue: stage tiles 0 and 1; publish tile 0
  STGA(0, 0); STGB(0, 0);
  STGA(1, 1); STGB(1, 1);
  asm volatile("s_waitcnt vmcnt(4)" ::: "memory");
  __builtin_amdgcn_s_barrier();

  int bc = 0, bs = 2;
  for (int tt = 0; tt < NT; ++tt) {
    const char* a = (const char*)sA + bc * 16384;
    const char* b = (const char*)sB + bc * 16384;
    const bool stg = (tt + 2 < NT);

    // ---------------- phase A: B-frags + A-frags 0..3, MFMA mi 0..3 ----------------
    short8v bfr[4], afr[4];
#pragma unroll
    for (int ni = 0; ni < 4; ni++) bfr[ni] = *(const short8v*)(b + bbase + ni * 1024);
#pragma unroll
    for (int mi = 0; mi < 4; mi++) afr[mi] = *(const short8v*)(a + abase + mi * 1024);
    if (stg) STGA(bs, tt + 2);
    SBAR();
    __builtin_amdgcn_s_barrier();
    asm volatile("s_waitcnt lgkmcnt(0)" ::: "memory");
    SBAR();                       // rule #18: MFMA must not hoist above this
    __builtin_amdgcn_s_setprio(1);
#pragma unroll
    for (int mi = 0; mi < 4; mi++)
#pragma unroll
      for (int ni = 0; ni < 4; ni++)
        acc[mi][ni] = __builtin_amdgcn_mfma_f32_16x16x32_bf16(afr[mi], bfr[ni], acc[mi][ni], 0, 0, 0);
    __builtin_amdgcn_s_setprio(0);
    SBAR();                       // MFMA must not sink below
    __builtin_amdgcn_s_barrier();

    // ---------------- phase B: A-frags 4..7, MFMA mi 4..7 ----------------
    short8v afr2[4];
#pragma unroll
    for (int mi = 0; mi < 4; mi++) afr2[mi] = *(const short8v*)(a + abase + (4 + mi) * 1024);
    if (stg) STGB(bs, tt + 2);
    SBAR();
    __builtin_amdgcn_s_barrier();
    asm volatile("s_waitcnt lgkmcnt(0)" ::: "memory");
    SBAR();
    __builtin_amdgcn_s_setprio(1);
#pragma unroll
    for (int mi = 0; mi < 4; mi++)
#pragma unroll
      for (int ni = 0; ni < 4; ni++)
        acc[4 + mi][ni] = __builtin_amdgcn_mfma_f32_16x16x32_bf16(afr2[mi], bfr[ni], acc[4 + mi][ni], 0, 0, 0);
    __builtin_amdgcn_s_setprio(0);
    SBAR();
    // publish tile tt+1 (counted: tile tt+2's 4 loads may stay in flight)
    if (tt < NT - 1) {
      if (stg) { asm volatile("s_waitcnt vmcnt(4)" ::: "memory"); }
      else     { asm volatile("s_waitcnt vmcnt(0)" ::: "memory"); }
    }
    __builtin_amdgcn_s_barrier();

    bc = (bc == 2) ? 0 : bc + 1;
    bs = (bs == 2) ? 0 : bs + 1;
  }
#undef STGA
#undef STGB
}

// ---- X = bf16(concat(sem, temp)) : [16384][2048] ----
__global__ void __launch_bounds__(256) k_prep_x(const float* __restrict__ sem,
                                                const float* __restrict__ temp,
                                                u16* __restrict__ X) {
  size_t i = (((size_t)blockIdx.x * 256) + threadIdx.x) << 2;
  int row = (int)(i >> 11);
  int col = (int)(i & 2047);
  const float* src = (col < 1024) ? (sem + (size_t)row * 1024 + col)
                                  : (temp + (size_t)row * 1024 + (col - 1024));
  float4 v = *(const float4*)src;
  ushort4 o;
  o.x = f2bf(v.x); o.y = f2bf(v.y); o.z = f2bf(v.z); o.w = f2bf(v.w);
  *(ushort4*)(X + i) = o;
}

// ---- Wt[n][k] = bf16(W[k][n]), W: [2048][1024] f32 ----
__global__ void __launch_bounds__(256) k_transpose_w(const float* __restrict__ W,
                                                     u16* __restrict__ Wt) {
  __shared__ float s[32][33];
  int tile = blockIdx.x;  // 64 k-tiles x 32 n-tiles
  int nt = tile & 31, kt = tile >> 5;
  int tx = threadIdx.x & 31, ty = threadIdx.x >> 5;  // ty: 0..7
  int n0 = nt << 5, k0 = kt << 5;
#pragma unroll
  for (int j = 0; j < 32; j += 8)
    s[ty + j][tx] = W[(size_t)(k0 + ty + j) * 1024 + (n0 + tx)];
  __syncthreads();
#pragma unroll
  for (int j = 0; j < 32; j += 8)
    Wt[(size_t)(n0 + ty + j) * 2048 + (k0 + tx)] = f2bf(s[tx][ty + j]);
}

// ---- fused QKV projection: X[16384][2048] @ WqkvT[3072][2048]^T ----
// tile decode is COLUMN-major so each XCD's concurrent blocks share ~1 W panel
__global__ void __launch_bounds__(512, 2) k_proj_qkv(const u16* __restrict__ X,
                                                     const u16* __restrict__ Wt,
                                                     const float* __restrict__ bq,
                                                     const float* __restrict__ bk,
                                                     const float* __restrict__ bv,
                                                     u16* __restrict__ Qb,
                                                     u16* __restrict__ Kb,
                                                     u16* __restrict__ Vt) {
  __shared__ __align__(16) u16 sA[3 * 8192];
  __shared__ __align__(16) u16 sB[3 * 8192];
  int tile = xcd_swz(blockIdx.x, 768);
  int bn = tile >> 6, bm = tile & 63;      // column-major: 64 m per n-column
  floatx4 acc[8][4];
  gemm256_core(X, K2, Wt, K2, bm * 256, bn * 256, K2, sA, sB, acc);

  const int t = threadIdx.x, w = t >> 6, l = t & 63;
  const int wr = w >> 2, wc = w & 3;
  const int r0 = bm * 256 + wr * 128 + ((l >> 4) << 2);
  const int cg0 = bn * 256 + wc * 64 + (l & 15);
  const int which = bn >> 2;  // 0:Q 1:K 2:V (each spans 4 column tiles)
  const float* bias = which == 0 ? bq : which == 1 ? bk : bv;
#pragma unroll
  for (int ni = 0; ni < 4; ni++) {
    int c1 = (cg0 + ni * 16) & 1023;
    float bvv = bias[c1];
#pragma unroll
    for (int mi = 0; mi < 8; mi++)
#pragma unroll
      for (int i = 0; i < 4; i++) {
        int rg = r0 + mi * 16 + i;
        u16 ob = f2bf(acc[mi][ni][i] + bvv);
        if (which == 0)      Qb[(size_t)rg * 1024 + c1] = ob;
        else if (which == 1) Kb[(size_t)rg * 1024 + c1] = ob;
        else                 Vt[((size_t)(rg >> 11) * 1024 + c1) * 2048 + (rg & 2047)] = ob;
      }
  }
}

// ---- gate[row] = sigmoid(X[row]·Wg + bg), one wave per row ----
__global__ void __launch_bounds__(256) k_gate(const u16* __restrict__ X, const float* __restrict__ Wg,
                                              const float* __restrict__ bg, float* __restrict__ gate) {
  int row = blockIdx.x * 4 + (threadIdx.x >> 6);
  int l = threadIdx.x & 63;
  const short* xr = (const short*)(X + (size_t)row * 2048);
  float s = 0.f;
#pragma unroll
  for (int i = 0; i < 4; i++) {
    int k = i * 512 + l * 8;
    short8v v = *(const short8v*)&xr[k];
#pragma unroll
    for (int j = 0; j < 8; j++) s += bf2f((u16)v[j]) * Wg[k + j];
  }
#pragma unroll
  for (int off = 32; off > 0; off >>= 1) s += __shfl_xor(s, off);
  if (l == 0) gate[row] = 1.f / (1.f + expf(-(s + bg[0])));
}

// ---- scores: E = exp(Q·K^T/32) bf16, row sums via atomics ----
__global__ void __launch_bounds__(512, 2) k_scores(const u16* __restrict__ Q, const u16* __restrict__ Kb,
                                                   u16* __restrict__ E, float* __restrict__ lsum) {
  __shared__ __align__(16) u16 sA[3 * 8192];
  __shared__ __align__(16) u16 sB[3 * 8192];
  int tile = xcd_swz(blockIdx.x, 512);
  int b = tile >> 6, r = tile & 63, bn = r >> 3, bm = r & 7;   // column-major in-batch
  const u16* A = Q + (size_t)b * NN * HH;
  const u16* Bt = Kb + (size_t)b * NN * HH;
  floatx4 acc[8][4];
  gemm256_core(A, HH, Bt, HH, bm * 256, bn * 256, HH, sA, sB, acc);

  u16* Eb = E + (size_t)b * NN * NN;
  float* lb = lsum + b * NN;
  const int t = threadIdx.x, w = t >> 6, l = t & 63;
  const int wr = w >> 2, wc = w & 3;
  const int q0 = bm * 256 + wr * 128 + ((l >> 4) << 2);
  const int k0c = bn * 256 + wc * 64 + (l & 15);
#pragma unroll
  for (int mi = 0; mi < 8; mi++)
#pragma unroll
    for (int i = 0; i < 4; i++) {
      int q = q0 + mi * 16 + i;
      float rs = 0.f;
#pragma unroll
      for (int ni = 0; ni < 4; ni++) {
        float e = expf(acc[mi][ni][i] * 0.03125f);
        Eb[(size_t)q * NN + k0c + ni * 16] = f2bf(e);
        rs += e;
      }
      rs += __shfl_xor(rs, 1);
      rs += __shfl_xor(rs, 2);
      rs += __shfl_xor(rs, 4);
      rs += __shfl_xor(rs, 8);
      if ((l & 15) == 0) atomicAdd(&lb[q], rs);
    }
}

// ---- PV: out = (gate/l)·(E @ V) + sem, f32 ----
__global__ void __launch_bounds__(512, 2) k_pv(const u16* __restrict__ E, const u16* __restrict__ Vt,
                                               const float* __restrict__ gate, const float* __restrict__ lsum,
                                               const float* __restrict__ sem, float* __restrict__ out) {
  __shared__ __align__(16) u16 sA[3 * 8192];
  __shared__ __align__(16) u16 sB[3 * 8192];
  int tile = xcd_swz(blockIdx.x, 256);
  int b = tile >> 5, r = tile & 31, bn = r >> 3, bm = r & 7;   // column-major in-batch
  const u16* A = E + (size_t)b * NN * NN;
  const u16* Bt = Vt + (size_t)b * HH * NN;
  floatx4 acc[8][4];
  gemm256_core(A, NN, Bt, NN, bm * 256, bn * 256, NN, sA, sB, acc);

  const int t = threadIdx.x, w = t >> 6, l = t & 63;
  const int wr = w >> 2, wc = w & 3;
  const int q0 = bm * 256 + wr * 128 + ((l >> 4) << 2);
  const int h0 = bn * 256 + wc * 64 + (l & 15);
#pragma unroll
  for (int mi = 0; mi < 8; mi++)
#pragma unroll
    for (int i = 0; i < 4; i++) {
      int q = q0 + mi * 16 + i;
      size_t gq = (size_t)b * NN + q;
      float wq = gate[gq] / lsum[gq];
#pragma unroll
      for (int ni = 0; ni < 4; ni++) {
        int h = h0 + ni * 16;
        out[gq * HH + h] = acc[mi][ni][i] * wq + sem[gq * HH + h];
      }
    }
}

// ---- column mean: cm[b][k] = (1/N) * sum_q (gate/l)_q * E[b][q][k] ----
__global__ void __launch_bounds__(256) k_colmean(const u16* __restrict__ E, const float* __restrict__ gate,
                                                 const float* __restrict__ lsum, float* __restrict__ cm) {
  __shared__ float wsh[256];
  int bid = blockIdx.x;           // 8 b x 8 kslice x 8 qchunk
  int b = bid >> 6, rest = bid & 63;
  int ks = rest >> 3, qc = rest & 7;
  int t = threadIdx.x;
  {
    size_t gq = (size_t)b * NN + qc * 256 + t;
    wsh[t] = gate[gq] / lsum[gq];
  }
  __syncthreads();
  int k = ks * 256 + t;
  const u16* Eb = E + ((size_t)b * NN + (size_t)qc * 256) * NN + k;
  float s = 0.f;
  for (int q = 0; q < 256; q++) s += wsh[q] * bf2f(Eb[(size_t)q * NN]);
  atomicAdd(&cm[b * NN + k], s * (1.f / 2048.f));
}

extern "C" void kernel_launch(void* const* d_in, const int* in_sizes, int n_in,
                              void* d_out, int out_size, void* d_ws, size_t ws_size,
                              hipStream_t stream) {
  const float* sem  = (const float*)d_in[0];
  const float* temp = (const float*)d_in[1];
  const float* Wq   = (const float*)d_in[2];
  const float* bq   = (const float*)d_in[3];
  const float* Wk   = (const float*)d_in[4];
  const float* bk   = (const float*)d_in[5];
  const float* Wv   = (const float*)d_in[6];
  const float* bv   = (const float*)d_in[7];
  const float* Wg   = (const float*)d_in[8];
  const float* bg   = (const float*)d_in[9];
  float* out = (float*)d_out;

  char* ws = (char*)d_ws;
  u16* X      = (u16*)ws;                      // 67,108,864 B (reused as E later)
  u16* E      = X;
  u16* WqkvT  = (u16*)(ws + 67108864);         // 3072x2048 bf16 = 12,582,912 B
  u16* Qb     = (u16*)(ws + 79691776);         // 33,554,432 B each
  u16* Kb     = (u16*)(ws + 113246208);
  u16* Vt     = (u16*)(ws + 146800640);
  float* gate = (float*)(ws + 180355072);      // 65,536 B
  float* lsum = (float*)(ws + 180420608);      // 65,536 B

  hipMemsetAsync(lsum, 0, 65536, stream);
  hipMemsetAsync(out + 16777216, 0, 65536, stream);  // colmean region of d_out

  k_prep_x<<<32768, 256, 0, stream>>>(sem, temp, X);
  k_transpose_w<<<2048, 256, 0, stream>>>(Wq, WqkvT);
  k_transpose_w<<<2048, 256, 0, stream>>>(Wk, WqkvT + (size_t)1024 * 2048);
  k_transpose_w<<<2048, 256, 0, stream>>>(Wv, WqkvT + (size_t)2048 * 2048);
  k_proj_qkv<<<768, 512, 0, stream>>>(X, WqkvT, bq, bk, bv, Qb, Kb, Vt);
  k_gate<<<4096, 256, 0, stream>>>(X, Wg, bg, gate);
  k_scores<<<512, 512, 0, stream>>>(Qb, Kb, E, lsum);   // overwrites X with E (X dead now)
  k_pv<<<256, 512, 0, stream>>>(E, Vt, gate, lsum, sem, out);
  k_colmean<<<512, 256, 0, stream>>>(E, gate, lsum, out + 16777216);
}

// Round 5
// 502.218 us; speedup vs baseline: 1.2250x; 1.2250x over previous
//
#include <hip/hip_runtime.h>
#include <stdint.h>
#include <math.h>

// B=8, N=2048, H=1024, 2H=2048, M=B*N=16384
#define NB 8
#define NN 2048
#define HH 1024
#define K2 2048
#define MM 16384

typedef unsigned short u16;
typedef __attribute__((ext_vector_type(8))) short short8v;
typedef __attribute__((ext_vector_type(4))) float floatx4;

__device__ __forceinline__ float bf2f(u16 u) { return __uint_as_float(((unsigned)u) << 16); }
__device__ __forceinline__ u16 f2bf(float f) {
  unsigned u = __float_as_uint(f);
  unsigned r = (u + 0x7fffu + ((u >> 16) & 1u)) >> 16;
  return (u16)r;
}

__device__ __forceinline__ void async16(const void* g, void* lds) {
  __builtin_amdgcn_global_load_lds((const __attribute__((address_space(1))) void*)g,
                                   (__attribute__((address_space(3))) void*)lds,
                                   16, 0, 0);
}

// bijective XCD swizzle: grids here are all multiples of 8
__device__ __forceinline__ int xcd_swz(int bid, int nblk) {
  return (bid & 7) * (nblk >> 3) + (bid >> 3);
}

#define SBAR() __builtin_amdgcn_sched_barrier(0)

// ======================================================================
// 128x128 tile GEMM core (m97-class geometry: 4 waves 2x2, 256 thr,
// per-wave 64x64 acc => 64 AGPR, ~160 total regs, 3 waves/SIMD so
// ~3 INDEPENDENT blocks/CU overlap each other's stalls - round-4 showed
// the 256^2 1-block/CU lockstep serializes MFMA/LDS/staging phases).
// Double-buffered LDS 32 KB, counted vmcnt(4): next tile's 4 loads stay
// in flight across BOTH raw s_barriers (no __syncthreads drain).
// LDS tile 128x32 bf16, 64B rows, 16B-chunk XOR swizzle
// phys = chunk ^ ((row>>1)&3): 0 bank conflicts (verified round 2).
// Bt is [N][K] K-major.
// ======================================================================
__device__ __forceinline__ void gemm128_core(const u16* __restrict__ A, int lda,
                                             const u16* __restrict__ Bt, int ldb,
                                             int rowA0, int rowB0, int K,
                                             u16* sA, u16* sB, floatx4 acc[4][4]) {
  const int t = threadIdx.x;       // 0..255
  const int w = t >> 6, l = t & 63;
  const int wr = w >> 1, wc = w & 1;

#pragma unroll
  for (int mi = 0; mi < 4; mi++)
#pragma unroll
    for (int ni = 0; ni < 4; ni++) { floatx4 z = {0.f,0.f,0.f,0.f}; acc[mi][ni] = z; }

  // staging: wave w, load j covers LDS rows w*32+j*16 .. +15; lane l -> (row srow=l>>2, chunk l&3)
  // source chunk inverse-swizzled: cs = (l&3) ^ ((l>>3)&3)  [(row>>1)&3 == (l>>3)&3]
  const int srow = l >> 2;
  const int cs = (((l & 3) ^ ((l >> 3) & 3)) << 3);
  const u16* gA0 = A + (size_t)(rowA0 + w * 32 + srow) * lda + cs;
  const u16* gA1 = A + (size_t)(rowA0 + w * 32 + 16 + srow) * lda + cs;
  const u16* gB0 = Bt + (size_t)(rowB0 + w * 32 + srow) * ldb + cs;
  const u16* gB1 = Bt + (size_t)(rowB0 + w * 32 + 16 + srow) * ldb + cs;
  char* dA = (char*)sA + w * 2048 + l * 16;   // + j*1024 + buf*8192
  char* dB = (char*)sB + w * 2048 + l * 16;

  // read side (swizzled): global chunk (l>>4) of row fr -> phys (l>>4)^((fr>>1)&3)
  const int fr = l & 15;
  const int ch = (((l >> 4) ^ ((fr >> 1) & 3)) << 4);
  const int abase = wr * 4096 + fr * 64 + ch;   // + mi*1024 (16 rows)
  const int bbase = wc * 4096 + fr * 64 + ch;   // + ni*1024

  const int NT = K >> 5;

#define STG128(bi, kt) { const int ko_ = (kt) << 5; const int bo_ = (bi) << 13; \
    async16(gA0 + ko_, dA + bo_); async16(gA1 + ko_, dA + bo_ + 1024);          \
    async16(gB0 + ko_, dB + bo_); async16(gB1 + ko_, dB + bo_ + 1024); }

  STG128(0, 0);
  for (int tt = 0; tt < NT; ++tt) {
    const int bc = tt & 1;
    if (tt + 1 < NT) {
      STG128(bc ^ 1, tt + 1);
      asm volatile("s_waitcnt vmcnt(4)" ::: "memory");  // tile tt done; tt+1 stays in flight
    } else {
      asm volatile("s_waitcnt vmcnt(0)" ::: "memory");
    }
    __builtin_amdgcn_s_barrier();          // publish tile tt

    const char* a = (const char*)sA + (bc << 13);
    const char* b = (const char*)sB + (bc << 13);
    short8v af[4], bf[4];
#pragma unroll
    for (int mi = 0; mi < 4; mi++) af[mi] = *(const short8v*)(a + abase + mi * 1024);
#pragma unroll
    for (int ni = 0; ni < 4; ni++) bf[ni] = *(const short8v*)(b + bbase + ni * 1024);
    __builtin_amdgcn_s_setprio(1);
#pragma unroll
    for (int mi = 0; mi < 4; mi++)
#pragma unroll
      for (int ni = 0; ni < 4; ni++)
        acc[mi][ni] = __builtin_amdgcn_mfma_f32_16x16x32_bf16(af[mi], bf[ni], acc[mi][ni], 0, 0, 0);
    __builtin_amdgcn_s_setprio(0);
    SBAR();                                 // pin reads+MFMA above the seal barrier
    __builtin_amdgcn_s_barrier();           // seal reads of buf bc before next STG overwrites
  }
#undef STG128
}

// ---- X = bf16(concat(sem,temp)) AND gate = sigmoid(combined.Wg + bg), one block per row ----
__global__ void __launch_bounds__(256) k_prep_gate(const float* __restrict__ sem,
                                                   const float* __restrict__ temp,
                                                   const float* __restrict__ Wg,
                                                   const float* __restrict__ bg,
                                                   u16* __restrict__ X, float* __restrict__ gate) {
  __shared__ float red[4];
  int row = blockIdx.x;
  int t = threadIdx.x, w = t >> 6, l = t & 63;
  const float* s0 = sem + (size_t)row * 1024 + t * 4;
  const float* t0 = temp + (size_t)row * 1024 + t * 4;
  u16* xr = X + (size_t)row * 2048;
  float4 a = *(const float4*)s0;
  float4 b = *(const float4*)t0;
  ushort4 oa = { f2bf(a.x), f2bf(a.y), f2bf(a.z), f2bf(a.w) };
  ushort4 ob = { f2bf(b.x), f2bf(b.y), f2bf(b.z), f2bf(b.w) };
  *(ushort4*)(xr + t * 4) = oa;
  *(ushort4*)(xr + 1024 + t * 4) = ob;
  float4 wa = *(const float4*)(Wg + t * 4);
  float4 wb = *(const float4*)(Wg + 1024 + t * 4);
  float s = a.x * wa.x + a.y * wa.y + a.z * wa.z + a.w * wa.w
          + b.x * wb.x + b.y * wb.y + b.z * wb.z + b.w * wb.w;
#pragma unroll
  for (int off = 32; off > 0; off >>= 1) s += __shfl_xor(s, off);
  if (l == 0) red[w] = s;
  __syncthreads();
  if (t == 0) {
    float tot = red[0] + red[1] + red[2] + red[3] + bg[0];
    gate[row] = 1.f / (1.f + expf(-tot));
  }
}

// ---- Wt[n][k] = bf16(W[k][n]), W: [2048][1024] f32 ----
__global__ void __launch_bounds__(256) k_transpose_w(const float* __restrict__ W,
                                                     u16* __restrict__ Wt) {
  __shared__ float s[32][33];
  int tile = blockIdx.x;  // 64 k-tiles x 32 n-tiles
  int nt = tile & 31, kt = tile >> 5;
  int tx = threadIdx.x & 31, ty = threadIdx.x >> 5;  // ty: 0..7
  int n0 = nt << 5, k0 = kt << 5;
#pragma unroll
  for (int j = 0; j < 32; j += 8)
    s[ty + j][tx] = W[(size_t)(k0 + ty + j) * 1024 + (n0 + tx)];
  __syncthreads();
#pragma unroll
  for (int j = 0; j < 32; j += 8)
    Wt[(size_t)(n0 + ty + j) * 2048 + (k0 + tx)] = f2bf(s[tx][ty + j]);
}

// ---- fused QKV projection: X[16384][2048] @ WqkvT[3072][2048]^T ----
__global__ void __launch_bounds__(256, 3) k_proj_qkv(const u16* __restrict__ X,
                                                     const u16* __restrict__ Wt,
                                                     const float* __restrict__ bq,
                                                     const float* __restrict__ bk,
                                                     const float* __restrict__ bv,
                                                     u16* __restrict__ Qb,
                                                     u16* __restrict__ Kb,
                                                     u16* __restrict__ Vt) {
  __shared__ __align__(16) u16 sA[2 * 4096];
  __shared__ __align__(16) u16 sB[2 * 4096];
  int tile = xcd_swz(blockIdx.x, 3072);
  int bm = tile / 24, bn = tile - bm * 24;   // row-major (round-2/3 proven FETCH)
  floatx4 acc[4][4];
  gemm128_core(X, K2, Wt, K2, bm * 128, bn * 128, K2, sA, sB, acc);

  const int t = threadIdx.x, w = t >> 6, l = t & 63;
  const int wr = w >> 1, wc = w & 1;
  const int r0 = bm * 128 + wr * 64 + ((l >> 4) << 2);
  const int c0 = (bn & 7) * 128 + wc * 64 + (l & 15);
  const int which = bn >> 3;  // 0:Q 1:K 2:V
  if (which == 2) {
#pragma unroll
    for (int ni = 0; ni < 4; ni++) {
      int h = c0 + ni * 16;
      float bvv = bv[h];
#pragma unroll
      for (int mi = 0; mi < 4; mi++) {
        int rg = r0 + mi * 16;                 // n%4==0, no batch crossing
        int b = rg >> 11, n = rg & 2047;
        ushort4 o = { f2bf(acc[mi][ni][0] + bvv), f2bf(acc[mi][ni][1] + bvv),
                      f2bf(acc[mi][ni][2] + bvv), f2bf(acc[mi][ni][3] + bvv) };
        *(ushort4*)&Vt[((size_t)b * 1024 + h) * 2048 + n] = o;
      }
    }
  } else {
    u16* Out = (which == 0) ? Qb : Kb;
    const float* bias = (which == 0) ? bq : bk;
#pragma unroll
    for (int ni = 0; ni < 4; ni++) {
      int c1 = c0 + ni * 16;
      float bvv = bias[c1];
#pragma unroll
      for (int mi = 0; mi < 4; mi++)
#pragma unroll
        for (int i = 0; i < 4; i++)
          Out[(size_t)(r0 + mi * 16 + i) * 1024 + c1] = f2bf(acc[mi][ni][i] + bvv);
    }
  }
}

// ---- scores: E = exp(Q.K^T/32) bf16, row sums via atomics ----
__global__ void __launch_bounds__(256, 3) k_scores(const u16* __restrict__ Q, const u16* __restrict__ Kb,
                                                   u16* __restrict__ E, float* __restrict__ lsum) {
  __shared__ __align__(16) u16 sA[2 * 4096];
  __shared__ __align__(16) u16 sB[2 * 4096];
  int tile = xcd_swz(blockIdx.x, 2048);
  int b = tile >> 8, r = tile & 255, bm = r >> 4, bn = r & 15;
  const u16* A = Q + (size_t)b * NN * HH;
  const u16* Bt = Kb + (size_t)b * NN * HH;
  floatx4 acc[4][4];
  gemm128_core(A, HH, Bt, HH, bm * 128, bn * 128, HH, sA, sB, acc);

  u16* Eb = E + (size_t)b * NN * NN;
  float* lb = lsum + b * NN;
  const int t = threadIdx.x, w = t >> 6, l = t & 63;
  const int wr = w >> 1, wc = w & 1;
  const int q0 = bm * 128 + wr * 64 + ((l >> 4) << 2);
  const int k0c = bn * 128 + wc * 64 + (l & 15);
#pragma unroll
  for (int mi = 0; mi < 4; mi++)
#pragma unroll
    for (int i = 0; i < 4; i++) {
      int q = q0 + mi * 16 + i;
      float rs = 0.f;
#pragma unroll
      for (int ni = 0; ni < 4; ni++) {
        float e = expf(acc[mi][ni][i] * 0.03125f);
        Eb[(size_t)q * NN + k0c + ni * 16] = f2bf(e);
        rs += e;
      }
      rs += __shfl_xor(rs, 1);
      rs += __shfl_xor(rs, 2);
      rs += __shfl_xor(rs, 4);
      rs += __shfl_xor(rs, 8);
      if ((l & 15) == 0) atomicAdd(&lb[q], rs);
    }
}

// ---- PV: out = (gate/l).(E @ V) + sem, f32 ----
__global__ void __launch_bounds__(256, 3) k_pv(const u16* __restrict__ E, const u16* __restrict__ Vt,
                                               const float* __restrict__ gate, const float* __restrict__ lsum,
                                               const float* __restrict__ sem, float* __restrict__ out) {
  __shared__ __align__(16) u16 sA[2 * 4096];
  __shared__ __align__(16) u16 sB[2 * 4096];
  int tile = xcd_swz(blockIdx.x, 1024);
  int b = tile >> 7, r = tile & 127, bm = r >> 3, bn = r & 7;
  const u16* A = E + (size_t)b * NN * NN;
  const u16* Bt = Vt + (size_t)b * HH * NN;
  floatx4 acc[4][4];
  gemm128_core(A, NN, Bt, NN, bm * 128, bn * 128, NN, sA, sB, acc);

  const int t = threadIdx.x, w = t >> 6, l = t & 63;
  const int wr = w >> 1, wc = w & 1;
  const int q0 = bm * 128 + wr * 64 + ((l >> 4) << 2);
  const int h0 = bn * 128 + wc * 64 + (l & 15);
#pragma unroll
  for (int mi = 0; mi < 4; mi++)
#pragma unroll
    for (int i = 0; i < 4; i++) {
      int q = q0 + mi * 16 + i;
      size_t gq = (size_t)b * NN + q;
      float wq = gate[gq] / lsum[gq];
#pragma unroll
      for (int ni = 0; ni < 4; ni++) {
        int h = h0 + ni * 16;
        out[gq * HH + h] = acc[mi][ni][i] * wq + sem[gq * HH + h];
      }
    }
}

// ---- column mean: cm[b][k] = (1/N) * sum_q (gate/l)_q * E[b][q][k] ----
__global__ void __launch_bounds__(256) k_colmean(const u16* __restrict__ E, const float* __restrict__ gate,
                                                 const float* __restrict__ lsum, float* __restrict__ cm) {
  __shared__ float wsh[256];
  int bid = blockIdx.x;           // 8 b x 8 kslice x 8 qchunk
  int b = bid >> 6, rest = bid & 63;
  int ks = rest >> 3, qc = rest & 7;
  int t = threadIdx.x;
  {
    size_t gq = (size_t)b * NN + qc * 256 + t;
    wsh[t] = gate[gq] / lsum[gq];
  }
  __syncthreads();
  int k = ks * 256 + t;
  const u16* Eb = E + ((size_t)b * NN + (size_t)qc * 256) * NN + k;
  float s = 0.f;
  for (int q = 0; q < 256; q++) s += wsh[q] * bf2f(Eb[(size_t)q * NN]);
  atomicAdd(&cm[b * NN + k], s * (1.f / 2048.f));
}

extern "C" void kernel_launch(void* const* d_in, const int* in_sizes, int n_in,
                              void* d_out, int out_size, void* d_ws, size_t ws_size,
                              hipStream_t stream) {
  const float* sem  = (const float*)d_in[0];
  const float* temp = (const float*)d_in[1];
  const float* Wq   = (const float*)d_in[2];
  const float* bq   = (const float*)d_in[3];
  const float* Wk   = (const float*)d_in[4];
  const float* bk   = (const float*)d_in[5];
  const float* Wv   = (const float*)d_in[6];
  const float* bv   = (const float*)d_in[7];
  const float* Wg   = (const float*)d_in[8];
  const float* bg   = (const float*)d_in[9];
  float* out = (float*)d_out;

  char* ws = (char*)d_ws;
  u16* X      = (u16*)ws;                      // 67,108,864 B (reused as E later)
  u16* E      = X;
  u16* WqkvT  = (u16*)(ws + 67108864);         // 3072x2048 bf16 = 12,582,912 B
  u16* Qb     = (u16*)(ws + 79691776);         // 33,554,432 B each
  u16* Kb     = (u16*)(ws + 113246208);
  u16* Vt     = (u16*)(ws + 146800640);
  float* gate = (float*)(ws + 180355072);      // 65,536 B
  float* lsum = (float*)(ws + 180420608);      // 65,536 B

  hipMemsetAsync(lsum, 0, 65536, stream);
  hipMemsetAsync(out + 16777216, 0, 65536, stream);  // colmean region of d_out

  k_prep_gate<<<16384, 256, 0, stream>>>(sem, temp, Wg, bg, X, gate);
  k_transpose_w<<<2048, 256, 0, stream>>>(Wq, WqkvT);
  k_transpose_w<<<2048, 256, 0, stream>>>(Wk, WqkvT + (size_t)1024 * 2048);
  k_transpose_w<<<2048, 256, 0, stream>>>(Wv, WqkvT + (size_t)2048 * 2048);
  k_proj_qkv<<<3072, 256, 0, stream>>>(X, WqkvT, bq, bk, bv, Qb, Kb, Vt);
  k_scores<<<2048, 256, 0, stream>>>(Qb, Kb, E, lsum);   // overwrites X with E (X dead now)
  k_pv<<<1024, 256, 0, stream>>>(E, Vt, gate, lsum, sem, out);
  k_colmean<<<512, 256, 0, stream>>>(E, gate, lsum, out + 16777216);
}